// Round 6
// baseline (11605.088 us; speedup 1.0000x reference)
//
#include <hip/hip_runtime.h>

#define NVOX 400000
#define K27 27
#define EPS_ 1e-5f

typedef short short8 __attribute__((ext_vector_type(8)));
typedef float floatx4 __attribute__((ext_vector_type(4)));
typedef unsigned int uintx4 __attribute__((ext_vector_type(4)));

// round-to-nearest-even fp32 -> bf16, packed pair (a low 16, b high 16)
__device__ __forceinline__ unsigned int pack2bf(float a, float b) {
    unsigned int ua = __builtin_bit_cast(unsigned int, a);
    unsigned int ub = __builtin_bit_cast(unsigned int, b);
    ua += 0x7fffu + ((ua >> 16) & 1u);
    ub += 0x7fffu + ((ub >> 16) & 1u);
    return (ua >> 16) | (ub & 0xffff0000u);
}

// blocks [0, fb): fp32->bf16 feature conversion (32 elems/thread)
// blocks [fb, fb+32): W[k][ci][co] -> wt[k][co][ci] bf16
// block  fb+32: zero the 128 stats accumulators
__global__ void prep_kernel(const float* __restrict__ w,
                            const float* __restrict__ feat,
                            unsigned short* __restrict__ feat_bf,
                            unsigned short* __restrict__ wt,
                            float* __restrict__ sums,
                            int fb) {
    const int b = blockIdx.x;
    const int t = threadIdx.x;
    if (b < fb) {
#pragma unroll
        for (int r = 0; r < 4; ++r) {
            const int i0 = b * 8192 + r * 2048 + t * 8;
            const floatx4* s = (const floatx4*)(feat + i0);
            const floatx4 f0 = s[0], f1 = s[1];
            uintx4 v;
            v[0] = pack2bf(f0[0], f0[1]); v[1] = pack2bf(f0[2], f0[3]);
            v[2] = pack2bf(f1[0], f1[1]); v[3] = pack2bf(f1[2], f1[3]);
            *(uintx4*)(feat_bf + i0) = v;
        }
    } else if (b < fb + 32) {
        for (int g = (b - fb) * 256 + t; g < K27 * 64 * 64; g += 32 * 256) {
            const int k = g >> 12, r = g & 4095, co = r >> 6, ci = r & 63;
            unsigned int u =
                __builtin_bit_cast(unsigned int, w[(k << 12) + (ci << 6) + co]);
            u += 0x7fffu + ((u >> 16) & 1u);
            wt[g] = (unsigned short)(u >> 16);
        }
    } else {
        if (t < 128) sums[t] = 0.0f;
    }
}

// 128 rows x 64 out-ch per block (3125 blocks, no tail). 4 waves, wave tile
// M=32 x N=64 -> 2x4 mfma_f32_16x16x32_bf16 per kb (acc 32 AGPR).
// Latency plan: (1) block's whole nmap slice cached in LDS up front ->
// in-loop idx reads are ~120cyc LDS broadcasts; (2) register ping-pong
// (areg/breg x2): gathers for k+1 issue BEFORE barrier1 of iter k and are
// consumed at ds_write of k+1 -> a full iteration in flight; (3) inactive
// (row,k) gathers and A ds_writes are skipped (~80%), af fragments masked
// to 0 at read so stale LDS never reaches acc. XOR-swizzled 16B chunks
// keep all LDS phases conflict-free. Stats fused into the epilogue.
template <bool BF16FEAT>
__launch_bounds__(256)
__global__ void conv_mfma(const float* __restrict__ feat,
                          const unsigned short* __restrict__ feat_bf,
                          const int* __restrict__ nmap,
                          const unsigned short* __restrict__ wt,
                          float* __restrict__ out,
                          float* __restrict__ sums) {
    __shared__ __align__(16) unsigned short a_tile[128 * 64];  // 16 KB
    __shared__ __align__(16) unsigned short b_tile[64 * 64];   //  8 KB
    __shared__ int idx_lds[K27 * 128];                         // 13.5 KB
    __shared__ float cstat[128];

    const int tid  = threadIdx.x;
    const int wv   = tid >> 6;
    const int lane = tid & 63;
    const int m    = lane & 15;
    const int q    = lane >> 4;
    const int base = blockIdx.x * 128;

    // ---- preamble: cache nmap[k][base..base+128) in LDS (coalesced)
    for (int j = tid; j < K27 * 128; j += 256)
        idx_lds[j] = nmap[(j >> 7) * NVOX + base + (j & 127)];
    if (tid < 128) cstat[tid] = 0.0f;
    __syncthreads();

    // ---- staging descriptors: thread owns A chunks c = tid+256j (j<4);
    // row = c>>3, 16B chunk gc = c&7 (8 consecutive lanes per row)
    const int gc = tid & 7;
    int arow[4], apos[4];
#pragma unroll
    for (int j = 0; j < 4; ++j) {
        const int c = tid + 256 * j;
        arow[j] = c >> 3;
        apos[j] = (arow[j] * 8 + (gc ^ (arow[j] & 7))) * 8;
    }
    int bsrc[2], bpos[2];
#pragma unroll
    for (int j = 0; j < 2; ++j) {
        const int c = tid + 256 * j;
        bsrc[j] = c * 8;
        bpos[j] = ((c >> 3) * 8 + ((c & 7) ^ ((c >> 3) & 7))) * 8;
    }
    int row_a[2];
#pragma unroll
    for (int mt = 0; mt < 2; ++mt) row_a[mt] = wv * 32 + mt * 16 + m;

    floatx4 acc[2][4];
#pragma unroll
    for (int mt = 0; mt < 2; ++mt)
#pragma unroll
        for (int nt = 0; nt < 4; ++nt)
            acc[mt][nt] = (floatx4){0.f, 0.f, 0.f, 0.f};

    short8 areg[2][4], breg[2][2];
    int idxc[2][4];

#define FETCH_SET(s, kk)                                                      \
    do {                                                                      \
        _Pragma("unroll") for (int j = 0; j < 4; ++j)                         \
            idxc[s][j] = idx_lds[(kk) * 128 + arow[j]];                       \
        _Pragma("unroll") for (int j = 0; j < 4; ++j) {                       \
            if (idxc[s][j] >= 0) {                                            \
                if (BF16FEAT) {                                               \
                    areg[s][j] = *(const short8*)(                            \
                        feat_bf + (size_t)idxc[s][j] * 64 + gc * 8);          \
                } else {                                                      \
                    const floatx4* sp = (const floatx4*)(                     \
                        feat + (size_t)idxc[s][j] * 64 + gc * 8);             \
                    const floatx4 f0 = sp[0], f1 = sp[1];                     \
                    uintx4 v;                                                 \
                    v[0] = pack2bf(f0[0], f0[1]);                             \
                    v[1] = pack2bf(f0[2], f0[3]);                             \
                    v[2] = pack2bf(f1[0], f1[1]);                             \
                    v[3] = pack2bf(f1[2], f1[3]);                             \
                    areg[s][j] = __builtin_bit_cast(short8, v);               \
                }                                                             \
            }                                                                 \
        }                                                                     \
        _Pragma("unroll") for (int j = 0; j < 2; ++j)                         \
            breg[s][j] = *(const short8*)(wt + (kk) * 4096 + bsrc[j]);        \
    } while (0)

    FETCH_SET(0, 0);

    for (int k = 0; k < K27; ++k) {
        const int cur = k & 1, nx = cur ^ 1;
        // issue k+1's gathers NOW -> in flight across write+barriers+MFMA
        if (k + 1 < K27) FETCH_SET(nx, k + 1);

        __syncthreads();  // all waves done MFMA-reading iter k-1's tiles
#pragma unroll
        for (int j = 0; j < 4; ++j)
            if (idxc[cur][j] >= 0) *(short8*)(a_tile + apos[j]) = areg[cur][j];
#pragma unroll
        for (int j = 0; j < 2; ++j) *(short8*)(b_tile + bpos[j]) = breg[cur][j];
        __syncthreads();  // writes visible

        // per-row activity for the af fragments of this k (LDS broadcast)
        bool am[2];
#pragma unroll
        for (int mt = 0; mt < 2; ++mt)
            am[mt] = idx_lds[k * 128 + row_a[mt]] >= 0;

#pragma unroll
        for (int kb = 0; kb < 2; ++kb) {
            short8 af[2], bf[4];
#pragma unroll
            for (int mt = 0; mt < 2; ++mt) {
                af[mt] = *(const short8*)(
                    a_tile + (row_a[mt] * 8 +
                              ((kb * 4 + q) ^ (row_a[mt] & 7))) * 8);
                if (!am[mt]) af[mt] = (short8){0, 0, 0, 0, 0, 0, 0, 0};
            }
#pragma unroll
            for (int nt = 0; nt < 4; ++nt) {
                const int row = nt * 16 + m;
                bf[nt] = *(const short8*)(
                    b_tile + (row * 8 + ((kb * 4 + q) ^ (row & 7))) * 8);
            }
#pragma unroll
            for (int mt = 0; mt < 2; ++mt)
#pragma unroll
                for (int nt = 0; nt < 4; ++nt)
                    acc[mt][nt] = __builtin_amdgcn_mfma_f32_16x16x32_bf16(
                        af[mt], bf[nt], acc[mt][nt], 0, 0, 0);
        }
    }
#undef FETCH_SET

    // epilogue: store (C/D: col=lane&15, row=q*4+reg — m89-verified) + stats
#pragma unroll
    for (int nt = 0; nt < 4; ++nt) {
        const int col = nt * 16 + m;
        float s = 0.f, s2 = 0.f;
#pragma unroll
        for (int mt = 0; mt < 2; ++mt) {
            const int row0 = base + wv * 32 + mt * 16 + q * 4;
#pragma unroll
            for (int i = 0; i < 4; ++i) {
                const float v = acc[mt][nt][i];
                s += v;
                s2 += v * v;
                out[(size_t)(row0 + i) * 64 + col] = v;
            }
        }
        atomicAdd(&cstat[col], s);
        atomicAdd(&cstat[64 + col], s2);
    }
    __syncthreads();
    if (tid < 128) atomicAdd(&sums[tid], cstat[tid]);
}

__global__ void bn_apply(float* __restrict__ out, const float* __restrict__ sums,
                         const float* __restrict__ gamma,
                         const float* __restrict__ beta) {
    __shared__ float sc[64];
    __shared__ float sh[64];
    const int tid = threadIdx.x;
    if (tid < 64) {
        const float inv_n = 1.0f / (float)NVOX;
        const float mean = sums[tid] * inv_n;
        const float var  = sums[64 + tid] * inv_n - mean * mean;
        const float g    = gamma[tid] * rsqrtf(var + EPS_);
        sc[tid] = g;
        sh[tid] = beta[tid] - mean * g;
    }
    __syncthreads();
    const int cg = (tid & 15) * 4;
    floatx4 scale, shift;
#pragma unroll
    for (int j = 0; j < 4; ++j) {
        scale[j] = sc[cg + j];
        shift[j] = sh[cg + j];
    }
    floatx4* p = (floatx4*)out;
    const int total4 = NVOX * 16;
    for (int i = blockIdx.x * 256 + tid; i < total4; i += gridDim.x * 256) {
        floatx4 v = p[i] * scale + shift;
#pragma unroll
        for (int j = 0; j < 4; ++j) v[j] = v[j] > 0.f ? v[j] : 0.f;
        p[i] = v;
    }
}

extern "C" void kernel_launch(void* const* d_in, const int* in_sizes, int n_in,
                              void* d_out, int out_size, void* d_ws, size_t ws_size,
                              hipStream_t stream) {
    const float* feat  = (const float*)d_in[0];
    const int*   nmap  = (const int*)d_in[1];
    const float* w     = (const float*)d_in[2];
    const float* gamma = (const float*)d_in[3];
    const float* beta  = (const float*)d_in[4];
    float* out = (float*)d_out;

    const size_t FEATB = (size_t)NVOX * 64 * 2;      // 51,200,000
    const size_t WTB   = (size_t)K27 * 64 * 64 * 2;  //    221,184
    const int conv_blocks = NVOX / 128;              // 3125 exactly

    if (ws_size >= FEATB + WTB + 512) {
        unsigned short* feat_bf = (unsigned short*)d_ws;
        unsigned short* wt      = (unsigned short*)((char*)d_ws + FEATB);
        float* sums             = (float*)((char*)d_ws + FEATB + WTB);
        prep_kernel<<<dim3(3158), dim3(256), 0, stream>>>(
            w, feat, feat_bf, wt, sums, 3125);
        conv_mfma<true><<<dim3(conv_blocks), dim3(256), 0, stream>>>(
            feat, feat_bf, nmap, wt, out, sums);
        bn_apply<<<dim3(1024), dim3(256), 0, stream>>>(out, sums, gamma, beta);
    } else {
        // fallback: fp32 gather + in-register pack (no feature buffer)
        unsigned short* wt = (unsigned short*)d_ws;
        float* sums        = (float*)((char*)d_ws + WTB);
        prep_kernel<<<dim3(33), dim3(256), 0, stream>>>(
            w, feat, nullptr, wt, sums, 0);
        conv_mfma<false><<<dim3(conv_blocks), dim3(256), 0, stream>>>(
            feat, nullptr, nmap, wt, out, sums);
        bn_apply<<<dim3(1024), dim3(256), 0, stream>>>(out, sums, gamma, beta);
    }
}

// Round 7
// 470.395 us; speedup vs baseline: 24.6709x; 24.6709x over previous
//
#include <hip/hip_runtime.h>

#define NVOX 400000
#define K27 27
#define EPS_ 1e-5f

typedef short short8 __attribute__((ext_vector_type(8)));
typedef float floatx4 __attribute__((ext_vector_type(4)));
typedef unsigned int uintx4 __attribute__((ext_vector_type(4)));

// round-to-nearest-even fp32 -> bf16, packed pair (a low 16, b high 16)
__device__ __forceinline__ unsigned int pack2bf(float a, float b) {
    unsigned int ua = __builtin_bit_cast(unsigned int, a);
    unsigned int ub = __builtin_bit_cast(unsigned int, b);
    ua += 0x7fffu + ((ua >> 16) & 1u);
    ub += 0x7fffu + ((ub >> 16) & 1u);
    return (ua >> 16) | (ub & 0xffff0000u);
}

// blocks [0, fb): fp32->bf16 feature conversion (32 elems/thread)
// blocks [fb, fb+32): W[k][ci][co] -> wt[k][co][ci] bf16
// block  fb+32: zero the 128 stats accumulators
__global__ void prep_kernel(const float* __restrict__ w,
                            const float* __restrict__ feat,
                            unsigned short* __restrict__ feat_bf,
                            unsigned short* __restrict__ wt,
                            float* __restrict__ sums,
                            int fb) {
    const int b = blockIdx.x;
    const int t = threadIdx.x;
    if (b < fb) {
#pragma unroll
        for (int r = 0; r < 4; ++r) {
            const int i0 = b * 8192 + r * 2048 + t * 8;
            const floatx4* s = (const floatx4*)(feat + i0);
            const floatx4 f0 = s[0], f1 = s[1];
            uintx4 v;
            v[0] = pack2bf(f0[0], f0[1]); v[1] = pack2bf(f0[2], f0[3]);
            v[2] = pack2bf(f1[0], f1[1]); v[3] = pack2bf(f1[2], f1[3]);
            *(uintx4*)(feat_bf + i0) = v;
        }
    } else if (b < fb + 32) {
        for (int g = (b - fb) * 256 + t; g < K27 * 64 * 64; g += 32 * 256) {
            const int k = g >> 12, r = g & 4095, co = r >> 6, ci = r & 63;
            unsigned int u =
                __builtin_bit_cast(unsigned int, w[(k << 12) + (ci << 6) + co]);
            u += 0x7fffu + ((u >> 16) & 1u);
            wt[g] = (unsigned short)(u >> 16);
        }
    } else {
        if (t < 128) sums[t] = 0.0f;
    }
}

// 128 rows x 64 out-ch per block (3125 blocks). 4 waves, wave tile M=32 x
// N=64 -> 2x4 mfma_f32_16x16x32_bf16 per kb (acc 32 AGPR).
// Latency plan (R6 theory, scratch-free impl): k-loop manually unrolled by
// 2 with STATICALLY-NAMED register sets A/B (no runtime-indexed arrays ->
// nothing spills). Gathers for k+1 issue before barrier 1 of iter k ->
// in flight across staging + both barriers + MFMAs (compiler emits partial
// vmcnt, not vmcnt(0)). nmap slice cached in LDS up front (idx reads are
// LDS broadcasts). Inactive (row,k): gather + A ds_write skipped, af
// masked to 0 at read. XOR-swizzled 16B chunks: all LDS phases conflict-free.
template <bool BF16FEAT>
__launch_bounds__(256)
__global__ void conv_mfma(const float* __restrict__ feat,
                          const unsigned short* __restrict__ feat_bf,
                          const int* __restrict__ nmap,
                          const unsigned short* __restrict__ wt,
                          float* __restrict__ out,
                          float* __restrict__ sums) {
    __shared__ __align__(16) unsigned short a_tile[128 * 64];  // 16 KB
    __shared__ __align__(16) unsigned short b_tile[64 * 64];   //  8 KB
    __shared__ int idx_lds[K27 * 128];                         // 13.5 KB
    __shared__ float cstat[128];

    const int tid  = threadIdx.x;
    const int wv   = tid >> 6;
    const int lane = tid & 63;
    const int m    = lane & 15;
    const int q    = lane >> 4;
    const int base = blockIdx.x * 128;

    // ---- preamble: cache nmap[k][base..base+128) in LDS (coalesced)
    for (int j = tid; j < K27 * 128; j += 256)
        idx_lds[j] = nmap[(j >> 7) * NVOX + base + (j & 127)];
    if (tid < 128) cstat[tid] = 0.0f;
    __syncthreads();

    // ---- staging descriptors: thread owns A chunks c = tid+256j (j<4);
    // row = c>>3, 16B chunk gc = c&7 (8 consecutive lanes per row)
    const int gc = tid & 7;
    int arow[4], apos[4];
#pragma unroll
    for (int j = 0; j < 4; ++j) {
        const int c = tid + 256 * j;
        arow[j] = c >> 3;
        apos[j] = (arow[j] * 8 + (gc ^ (arow[j] & 7))) * 8;
    }
    int bsrc[2], bpos[2];
#pragma unroll
    for (int j = 0; j < 2; ++j) {
        const int c = tid + 256 * j;
        bsrc[j] = c * 8;
        bpos[j] = ((c >> 3) * 8 + ((c & 7) ^ ((c >> 3) & 7))) * 8;
    }
    int row_a[2];
#pragma unroll
    for (int mt = 0; mt < 2; ++mt) row_a[mt] = wv * 32 + mt * 16 + m;

    floatx4 acc[2][4];
#pragma unroll
    for (int mt = 0; mt < 2; ++mt)
#pragma unroll
        for (int nt = 0; nt < 4; ++nt)
            acc[mt][nt] = (floatx4){0.f, 0.f, 0.f, 0.f};

    short8 aregA[4], bregA[2];
    short8 aregB[4], bregB[2];
    int idxA[4], idxB[4];

#define FETCH_SET(areg, breg, idxc, kk)                                       \
    do {                                                                      \
        _Pragma("unroll") for (int j = 0; j < 4; ++j)                         \
            idxc[j] = idx_lds[(kk) * 128 + arow[j]];                          \
        _Pragma("unroll") for (int j = 0; j < 4; ++j) {                       \
            if (idxc[j] >= 0) {                                               \
                if (BF16FEAT) {                                               \
                    areg[j] = *(const short8*)(                               \
                        feat_bf + (size_t)idxc[j] * 64 + gc * 8);             \
                } else {                                                      \
                    const floatx4* sp = (const floatx4*)(                     \
                        feat + (size_t)idxc[j] * 64 + gc * 8);                \
                    const floatx4 f0 = sp[0], f1 = sp[1];                     \
                    uintx4 v;                                                 \
                    v[0] = pack2bf(f0[0], f0[1]);                             \
                    v[1] = pack2bf(f0[2], f0[3]);                             \
                    v[2] = pack2bf(f1[0], f1[1]);                             \
                    v[3] = pack2bf(f1[2], f1[3]);                             \
                    areg[j] = __builtin_bit_cast(short8, v);                  \
                }                                                             \
            }                                                                 \
        }                                                                     \
        _Pragma("unroll") for (int j = 0; j < 2; ++j)                         \
            breg[j] = *(const short8*)(wt + (kk) * 4096 + bsrc[j]);           \
    } while (0)

#define STAGE_SET(areg, breg, idxc)                                           \
    do {                                                                      \
        _Pragma("unroll") for (int j = 0; j < 4; ++j)                         \
            if (idxc[j] >= 0) *(short8*)(a_tile + apos[j]) = areg[j];         \
        _Pragma("unroll") for (int j = 0; j < 2; ++j)                         \
            *(short8*)(b_tile + bpos[j]) = breg[j];                           \
    } while (0)

#define COMPUTE(kk)                                                           \
    do {                                                                      \
        bool am[2];                                                           \
        _Pragma("unroll") for (int mt = 0; mt < 2; ++mt)                      \
            am[mt] = idx_lds[(kk) * 128 + row_a[mt]] >= 0;                    \
        _Pragma("unroll") for (int kb = 0; kb < 2; ++kb) {                    \
            short8 af[2], bf[4];                                              \
            _Pragma("unroll") for (int mt = 0; mt < 2; ++mt) {                \
                af[mt] = *(const short8*)(                                    \
                    a_tile + (row_a[mt] * 8 +                                 \
                              ((kb * 4 + q) ^ (row_a[mt] & 7))) * 8);         \
                if (!am[mt]) af[mt] = (short8){0, 0, 0, 0, 0, 0, 0, 0};       \
            }                                                                 \
            _Pragma("unroll") for (int nt = 0; nt < 4; ++nt) {                \
                const int row = nt * 16 + m;                                  \
                bf[nt] = *(const short8*)(                                    \
                    b_tile + (row * 8 + ((kb * 4 + q) ^ (row & 7))) * 8);     \
            }                                                                 \
            _Pragma("unroll") for (int mt = 0; mt < 2; ++mt)                  \
                _Pragma("unroll") for (int nt = 0; nt < 4; ++nt)              \
                    acc[mt][nt] = __builtin_amdgcn_mfma_f32_16x16x32_bf16(    \
                        af[mt], bf[nt], acc[mt][nt], 0, 0, 0);                \
        }                                                                     \
    } while (0)

    FETCH_SET(aregA, bregA, idxA, 0);

    for (int kk = 0; kk < K27; kk += 2) {
        // ---- iter kk (set A); prefetch kk+1 into B first
        if (kk + 1 < K27) FETCH_SET(aregB, bregB, idxB, kk + 1);
        __syncthreads();  // all waves done reading iter kk-1's tiles
        STAGE_SET(aregA, bregA, idxA);
        __syncthreads();  // writes visible
        COMPUTE(kk);
        if (kk + 1 >= K27) break;
        // ---- iter kk+1 (set B); prefetch kk+2 into A first
        if (kk + 2 < K27) FETCH_SET(aregA, bregA, idxA, kk + 2);
        __syncthreads();
        STAGE_SET(aregB, bregB, idxB);
        __syncthreads();
        COMPUTE(kk + 1);
    }
#undef FETCH_SET
#undef STAGE_SET
#undef COMPUTE

    // epilogue: store (C/D: col=lane&15, row=q*4+reg — m89-verified) + stats
#pragma unroll
    for (int nt = 0; nt < 4; ++nt) {
        const int col = nt * 16 + m;
        float s = 0.f, s2 = 0.f;
#pragma unroll
        for (int mt = 0; mt < 2; ++mt) {
            const int row0 = base + wv * 32 + mt * 16 + q * 4;
#pragma unroll
            for (int i = 0; i < 4; ++i) {
                const float v = acc[mt][nt][i];
                s += v;
                s2 += v * v;
                out[(size_t)(row0 + i) * 64 + col] = v;
            }
        }
        atomicAdd(&cstat[col], s);
        atomicAdd(&cstat[64 + col], s2);
    }
    __syncthreads();
    if (tid < 128) atomicAdd(&sums[tid], cstat[tid]);
}

__global__ void bn_apply(float* __restrict__ out, const float* __restrict__ sums,
                         const float* __restrict__ gamma,
                         const float* __restrict__ beta) {
    __shared__ float sc[64];
    __shared__ float sh[64];
    const int tid = threadIdx.x;
    if (tid < 64) {
        const float inv_n = 1.0f / (float)NVOX;
        const float mean = sums[tid] * inv_n;
        const float var  = sums[64 + tid] * inv_n - mean * mean;
        const float g    = gamma[tid] * rsqrtf(var + EPS_);
        sc[tid] = g;
        sh[tid] = beta[tid] - mean * g;
    }
    __syncthreads();
    const int cg = (tid & 15) * 4;
    floatx4 scale, shift;
#pragma unroll
    for (int j = 0; j < 4; ++j) {
        scale[j] = sc[cg + j];
        shift[j] = sh[cg + j];
    }
    floatx4* p = (floatx4*)out;
    const int total4 = NVOX * 16;
    for (int i = blockIdx.x * 256 + tid; i < total4; i += gridDim.x * 256) {
        floatx4 v = p[i] * scale + shift;
#pragma unroll
        for (int j = 0; j < 4; ++j) v[j] = v[j] > 0.f ? v[j] : 0.f;
        p[i] = v;
    }
}

extern "C" void kernel_launch(void* const* d_in, const int* in_sizes, int n_in,
                              void* d_out, int out_size, void* d_ws, size_t ws_size,
                              hipStream_t stream) {
    const float* feat  = (const float*)d_in[0];
    const int*   nmap  = (const int*)d_in[1];
    const float* w     = (const float*)d_in[2];
    const float* gamma = (const float*)d_in[3];
    const float* beta  = (const float*)d_in[4];
    float* out = (float*)d_out;

    const size_t FEATB = (size_t)NVOX * 64 * 2;      // 51,200,000
    const size_t WTB   = (size_t)K27 * 64 * 64 * 2;  //    221,184
    const int conv_blocks = NVOX / 128;              // 3125 exactly

    if (ws_size >= FEATB + WTB + 512) {
        unsigned short* feat_bf = (unsigned short*)d_ws;
        unsigned short* wt      = (unsigned short*)((char*)d_ws + FEATB);
        float* sums             = (float*)((char*)d_ws + FEATB + WTB);
        prep_kernel<<<dim3(3158), dim3(256), 0, stream>>>(
            w, feat, feat_bf, wt, sums, 3125);
        conv_mfma<true><<<dim3(conv_blocks), dim3(256), 0, stream>>>(
            feat, feat_bf, nmap, wt, out, sums);
        bn_apply<<<dim3(1024), dim3(256), 0, stream>>>(out, sums, gamma, beta);
    } else {
        // fallback: fp32 gather + in-register pack (no feature buffer)
        unsigned short* wt = (unsigned short*)d_ws;
        float* sums        = (float*)((char*)d_ws + WTB);
        prep_kernel<<<dim3(33), dim3(256), 0, stream>>>(
            w, feat, nullptr, wt, sums, 0);
        conv_mfma<false><<<dim3(conv_blocks), dim3(256), 0, stream>>>(
            feat, nullptr, nmap, wt, out, sums);
        bn_apply<<<dim3(1024), dim3(256), 0, stream>>>(out, sums, gamma, beta);
    }
}